// Round 1
// baseline (209.929 us; speedup 1.0000x reference)
//
#include <hip/hip_runtime.h>
#include <math.h>

// ---- problem constants (fixed by reference) ----
#define X_MIN_F   (-51.2f)
#define X_MAX_F   ( 51.2f)
#define RES_F     ( 0.2f)
#define BEV_W     512
#define BEV_H     512
#define NUM_CELLS (BEV_W * BEV_H)      // 262144
#define C_CLS     10
#define D_BOX     7
#define BATCH     8
#define NPTS      128

// Workspace layout (doubles): [0]=sum_bce_all, [1]=cls_correction (sum z at
// unique (b,idx,lbl)), [2]=box_sl1_sum, [3]=reg_count.

// ---------------------------------------------------------------------------
// Kernel A: per-batch GT scatter analysis. One block per batch, one thread per
// GT point. Dedup in LDS (O(N^2) = 16K cheap compares per block):
//   - firstCls: first occurrence of (idx,lbl)  -> contributes -z correction
//   - firstReg: first occurrence of idx        -> contributes reg count
//   - lastBox : LAST valid occurrence of idx   -> owns box target (sequential
//               scatter .set semantics: last write wins)
// ---------------------------------------------------------------------------
__global__ __launch_bounds__(NPTS)
void bev_scatter_kernel(const float* __restrict__ cls_logits,
                        const float* __restrict__ box_preds,
                        const float* __restrict__ gt_boxes,
                        const int*   __restrict__ gt_labels,
                        const float* __restrict__ gt_masks,
                        double* __restrict__ ws)
{
    const int b = blockIdx.x;
    const int n = threadIdx.x;

    __shared__ int s_idx[NPTS];
    __shared__ int s_lbl[NPTS];

    const float* gb = gt_boxes + ((size_t)b * NPTS + n) * D_BOX;
    const float x = gb[0];
    const float y = gb[1];
    const float m = gt_masks[b * NPTS + n];
    const int   lраw_dummy = 0; (void)lраw_dummy;
    const int   lraw = gt_labels[b * NPTS + n];

    const bool valid = (m > 0.5f) && (lraw >= 0) &&
                       (x >= X_MIN_F) && (x <= X_MAX_F) &&
                       (y >= X_MIN_F) && (y <= X_MAX_F);

    // match jnp: trunc((x - X_MIN)/RES) as f32 divide, then clip
    int gx = (int)((x - X_MIN_F) / RES_F);
    int gy = (int)((y - X_MIN_F) / RES_F);
    gx = min(max(gx, 0), BEV_W - 1);
    gy = min(max(gy, 0), BEV_H - 1);
    const int idx = gy * BEV_W + gx;
    const int lbl = (lraw < 0) ? 0 : lraw;

    s_idx[n] = valid ? idx : -1;
    s_lbl[n] = lbl;
    __syncthreads();

    if (s_idx[n] >= 0) {
        bool firstReg = true, firstCls = true, lastBox = true;
        const int my_idx = s_idx[n];
        const int my_lbl = s_lbl[n];
        #pragma unroll 8
        for (int k = 0; k < NPTS; ++k) {
            if (k == n || s_idx[k] != my_idx) continue;
            if (k < n) {
                firstReg = false;
                if (s_lbl[k] == my_lbl) firstCls = false;
            } else {
                lastBox = false;           // a later point overwrites this cell
            }
        }

        if (firstCls) {
            const float z = cls_logits[((size_t)b * NUM_CELLS + my_idx) * C_CLS + my_lbl];
            atomicAdd(&ws[1], (double)z);
        }
        if (firstReg) {
            atomicAdd(&ws[3], 1.0);
        }
        if (lastBox) {
            const float* bp = box_preds + ((size_t)b * NUM_CELLS + my_idx) * D_BOX;
            float s = 0.0f;
            #pragma unroll
            for (int d = 0; d < D_BOX; ++d) {
                const float diff = bp[d] - gb[d];
                const float ad = fabsf(diff);
                s += (ad < 1.0f) ? 0.5f * diff * diff : (ad - 0.5f);
            }
            atomicAdd(&ws[2], (double)s);
        }
    }
}

// ---------------------------------------------------------------------------
// Kernel B: streaming reduction  sum over all logits of bce(z, 0)
//           = max(z,0) + log1p(exp(-|z|))   (stable softplus)
// float4 loads (16 B/lane), grid-stride, wave shuffle reduce, double atomic.
// ---------------------------------------------------------------------------
__global__ __launch_bounds__(256)
void bce_sum_kernel(const float* __restrict__ z, unsigned int n_total,
                    double* __restrict__ ws)
{
    const unsigned int n4 = n_total >> 2;           // exact: 20,971,520 % 4 == 0
    const float4* __restrict__ z4 = (const float4*)z;

    float acc = 0.0f;
    unsigned int i = blockIdx.x * blockDim.x + threadIdx.x;
    const unsigned int stride = gridDim.x * blockDim.x;
    for (; i < n4; i += stride) {
        const float4 v = z4[i];
        acc += fmaxf(v.x, 0.0f) + log1pf(expf(-fabsf(v.x)));
        acc += fmaxf(v.y, 0.0f) + log1pf(expf(-fabsf(v.y)));
        acc += fmaxf(v.z, 0.0f) + log1pf(expf(-fabsf(v.z)));
        acc += fmaxf(v.w, 0.0f) + log1pf(expf(-fabsf(v.w)));
    }

    // wave64 shuffle reduce
    #pragma unroll
    for (int off = 32; off > 0; off >>= 1)
        acc += __shfl_down(acc, off);

    __shared__ float wsum[4];                       // 256 threads = 4 waves
    const int lane = threadIdx.x & 63;
    const int wid  = threadIdx.x >> 6;
    if (lane == 0) wsum[wid] = acc;
    __syncthreads();
    if (threadIdx.x == 0) {
        const float blk = wsum[0] + wsum[1] + wsum[2] + wsum[3];
        atomicAdd(&ws[0], (double)blk);
    }
}

// ---------------------------------------------------------------------------
// Finalize: combine the accumulators into [total, cls_loss, box_loss].
// ---------------------------------------------------------------------------
__global__ void finalize_kernel(const double* __restrict__ ws,
                                float* __restrict__ out)
{
    const double cls = (ws[0] - ws[1]) / (double)((size_t)BATCH * NUM_CELLS);
    const double box = ws[2] / (ws[3] + 1e-6);
    out[0] = (float)(cls + box);   // CLS_WEIGHT = BOX_WEIGHT = 1.0
    out[1] = (float)cls;
    out[2] = (float)box;
}

// ---------------------------------------------------------------------------
extern "C" void kernel_launch(void* const* d_in, const int* in_sizes, int n_in,
                              void* d_out, int out_size, void* d_ws, size_t ws_size,
                              hipStream_t stream)
{
    const float* cls_logits = (const float*)d_in[0];   // [8, 262144, 10] f32
    const float* box_preds  = (const float*)d_in[1];   // [8, 262144, 7]  f32
    const float* gt_boxes   = (const float*)d_in[2];   // [8, 128, 7]     f32
    const int*   gt_labels  = (const int*)  d_in[3];   // [8, 128]        int
    const float* gt_masks   = (const float*)d_in[4];   // [8, 128]        f32
    float*  out = (float*)d_out;                       // [3] f32
    double* ws  = (double*)d_ws;

    // d_ws is poisoned to 0xAA before every call -> zero accumulators.
    hipMemsetAsync(d_ws, 0, 4 * sizeof(double), stream);

    // Tiny scatter/dedup/gather kernel (independent of big reduction).
    bev_scatter_kernel<<<BATCH, NPTS, 0, stream>>>(
        cls_logits, box_preds, gt_boxes, gt_labels, gt_masks, ws);

    // Big streaming softplus reduction over cls_logits (83.9 MB read).
    const unsigned int n_total = (unsigned int)in_sizes[0];  // 20,971,520
    bce_sum_kernel<<<2048, 256, 0, stream>>>(cls_logits, n_total, ws);

    finalize_kernel<<<1, 1, 0, stream>>>(ws, out);
}

// Round 4
// 178.132 us; speedup vs baseline: 1.1785x; 1.1785x over previous
//
#include <hip/hip_runtime.h>
#include <math.h>

// ---- problem constants (fixed by reference) ----
#define X_MIN_F   (-51.2f)
#define X_MAX_F   ( 51.2f)
#define RES_F     ( 0.2f)
#define BEV_W     512
#define BEV_H     512
#define NUM_CELLS (BEV_W * BEV_H)      // 262144
#define C_CLS     10
#define D_BOX     7
#define BATCH     8
#define NPTS      128
#define NPART     2048                 // bce partial count (= grid of kernel 1)

#define LOG2E_F   1.4426950408889634f
#define LN2_F     0.6931471805599453f

// Hardware transcendentals: v_exp_f32 computes 2^x, v_log_f32 computes log2(x).
// Device pass: builtins exist -> use them. Host pass: fall back to asm stubs
// (parsed but never codegen'd for host).
#if defined(__has_builtin)
#if __has_builtin(__builtin_amdgcn_exp2f)
#define FAST_EXP2(x) __builtin_amdgcn_exp2f(x)
#endif
#if __has_builtin(__builtin_amdgcn_logf)
#define FAST_LOG2(x) __builtin_amdgcn_logf(x)
#endif
#endif
#ifndef FAST_EXP2
__device__ __forceinline__ float __fast_exp2_asm(float x) {
    float r; asm volatile("v_exp_f32 %0, %1" : "=v"(r) : "v"(x)); return r;
}
#define FAST_EXP2(x) __fast_exp2_asm(x)
#endif
#ifndef FAST_LOG2
__device__ __forceinline__ float __fast_log2_asm(float x) {
    float r; asm volatile("v_log_f32 %0, %1" : "=v"(r) : "v"(x)); return r;
}
#define FAST_LOG2(x) __fast_log2_asm(x)
#endif

// softplus(z) = bce(z, t=0) = max(z,0) + ln2 * log2(1 + 2^(-log2e*|z|))
__device__ __forceinline__ float softplus_hw(float z) {
    const float e = FAST_EXP2(-LOG2E_F * fabsf(z));
    return fmaxf(z, 0.0f) + LN2_F * FAST_LOG2(1.0f + e);
}

// ---------------------------------------------------------------------------
// Kernel 1: streaming softplus partial sums over cls_logits (83.9 MB read).
// Each of the NPART blocks writes ONE float partial (no atomics, no memset —
// every slot written unconditionally every call; graph-capture safe).
// ---------------------------------------------------------------------------
__global__ __launch_bounds__(256)
void bce_partials_kernel(const float* __restrict__ z, unsigned int n_total,
                         float* __restrict__ partials)
{
    const unsigned int n4 = n_total >> 2;           // 20,971,520 % 4 == 0
    const float4* __restrict__ z4 = (const float4*)z;

    float a0 = 0.0f, a1 = 0.0f, a2 = 0.0f, a3 = 0.0f;
    unsigned int i = blockIdx.x * blockDim.x + threadIdx.x;
    const unsigned int stride = gridDim.x * blockDim.x;
    for (; i < n4; i += stride) {
        const float4 v = z4[i];
        a0 += softplus_hw(v.x);
        a1 += softplus_hw(v.y);
        a2 += softplus_hw(v.z);
        a3 += softplus_hw(v.w);
    }
    float acc = (a0 + a1) + (a2 + a3);

    // wave64 shuffle reduce
    #pragma unroll
    for (int off = 32; off > 0; off >>= 1)
        acc += __shfl_down(acc, off);

    __shared__ float wsum[4];                       // 256 threads = 4 waves
    const int lane = threadIdx.x & 63;
    const int wid  = threadIdx.x >> 6;
    if (lane == 0) wsum[wid] = acc;
    __syncthreads();
    if (threadIdx.x == 0)
        partials[blockIdx.x] = wsum[0] + wsum[1] + wsum[2] + wsum[3];
}

// ---------------------------------------------------------------------------
// Kernel 2 (single block, 1024 threads): everything else.
//  (a) thread t = b*128+n handles GT point n of batch b: validity, cell index,
//      O(N^2) LDS dedup within the batch:
//        firstCls (idx,lbl first occurrence) -> -z correction (gather logit)
//        firstReg (idx first occurrence)     -> reg count
//        lastBox  (idx LAST occurrence)      -> smooth-L1 vs gathered box_pred
//      (sequential .set semantics: last write wins the cell)
//  (b) reduce the NPART bce partials in double
//  (c) combine and write [total, cls_loss, box_loss]
// ---------------------------------------------------------------------------
__global__ __launch_bounds__(1024)
void finalize_kernel(const float* __restrict__ cls_logits,
                     const float* __restrict__ box_preds,
                     const float* __restrict__ gt_boxes,
                     const int*   __restrict__ gt_labels,
                     const float* __restrict__ gt_masks,
                     const float* __restrict__ partials,
                     float* __restrict__ out)
{
    const int t = threadIdx.x;          // 0..1023
    const int b = t >> 7;               // batch index
    const int lane = t & 63;
    const int wid  = t >> 6;            // 0..15

    __shared__ int    s_idx[BATCH * NPTS];
    __shared__ int    s_lbl[BATCH * NPTS];
    __shared__ float  s_c[16], s_b[16], s_r[16];
    __shared__ double s_p[16];

    // ---- (a) scatter analysis ----
    const float* gb = gt_boxes + (size_t)t * D_BOX;
    const float x = gb[0];
    const float y = gb[1];
    const float m = gt_masks[t];
    const int   lraw = gt_labels[t];

    const bool valid = (m > 0.5f) && (lraw >= 0) &&
                       (x >= X_MIN_F) && (x <= X_MAX_F) &&
                       (y >= X_MIN_F) && (y <= X_MAX_F);

    int gx = (int)((x - X_MIN_F) / RES_F);   // f32 divide, trunc — matches jnp
    int gy = (int)((y - X_MIN_F) / RES_F);
    gx = min(max(gx, 0), BEV_W - 1);
    gy = min(max(gy, 0), BEV_H - 1);
    const int idx = gy * BEV_W + gx;
    const int lbl = (lraw < 0) ? 0 : lraw;

    s_idx[t] = valid ? idx : -1;
    s_lbl[t] = lbl;
    __syncthreads();

    float corr = 0.0f, boxs = 0.0f, regc = 0.0f;
    if (s_idx[t] >= 0) {
        bool firstReg = true, firstCls = true, lastBox = true;
        const int base = b << 7;                    // batch-local dedup window
        #pragma unroll 8
        for (int k = base; k < base + NPTS; ++k) {
            if (k == t || s_idx[k] != idx) continue;
            if (k < t) {
                firstReg = false;
                if (s_lbl[k] == lbl) firstCls = false;
            } else {
                lastBox = false;                    // later write wins the cell
            }
        }
        if (firstCls)
            corr = cls_logits[((size_t)b * NUM_CELLS + idx) * C_CLS + lbl];
        if (firstReg)
            regc = 1.0f;
        if (lastBox) {
            const float* bp = box_preds + ((size_t)b * NUM_CELLS + idx) * D_BOX;
            float s = 0.0f;
            #pragma unroll
            for (int d = 0; d < D_BOX; ++d) {
                const float diff = bp[d] - gb[d];
                const float ad = fabsf(diff);
                s += (ad < 1.0f) ? 0.5f * diff * diff : (ad - 0.5f);
            }
            boxs = s;
        }
    }
    #pragma unroll
    for (int off = 32; off > 0; off >>= 1) {
        corr += __shfl_down(corr, off);
        boxs += __shfl_down(boxs, off);
        regc += __shfl_down(regc, off);
    }
    if (lane == 0) { s_c[wid] = corr; s_b[wid] = boxs; s_r[wid] = regc; }

    // ---- (b) bce partial reduction (double) ----
    double p = (double)partials[t] + (double)partials[t + 1024];
    #pragma unroll
    for (int off = 32; off > 0; off >>= 1)
        p += __shfl_down(p, off);
    if (lane == 0) s_p[wid] = p;
    __syncthreads();

    // ---- (c) combine ----
    if (t == 0) {
        double sum_bce = 0.0, sum_corr = 0.0, sum_box = 0.0, sum_reg = 0.0;
        #pragma unroll
        for (int w = 0; w < 16; ++w) {
            sum_bce  += s_p[w];
            sum_corr += (double)s_c[w];
            sum_box  += (double)s_b[w];
            sum_reg  += (double)s_r[w];
        }
        const double cls = (sum_bce - sum_corr) / (double)((size_t)BATCH * NUM_CELLS);
        const double box = sum_box / (sum_reg + 1e-6);
        out[0] = (float)(cls + box);    // CLS_WEIGHT = BOX_WEIGHT = 1.0
        out[1] = (float)cls;
        out[2] = (float)box;
    }
}

// ---------------------------------------------------------------------------
extern "C" void kernel_launch(void* const* d_in, const int* in_sizes, int n_in,
                              void* d_out, int out_size, void* d_ws, size_t ws_size,
                              hipStream_t stream)
{
    const float* cls_logits = (const float*)d_in[0];   // [8, 262144, 10] f32
    const float* box_preds  = (const float*)d_in[1];   // [8, 262144, 7]  f32
    const float* gt_boxes   = (const float*)d_in[2];   // [8, 128, 7]     f32
    const int*   gt_labels  = (const int*)  d_in[3];   // [8, 128]        int
    const float* gt_masks   = (const float*)d_in[4];   // [8, 128]        f32
    float* out      = (float*)d_out;                   // [3] f32
    float* partials = (float*)d_ws;                    // [NPART] f32

    const unsigned int n_total = (unsigned int)in_sizes[0];  // 20,971,520

    bce_partials_kernel<<<NPART, 256, 0, stream>>>(cls_logits, n_total, partials);

    finalize_kernel<<<1, 1024, 0, stream>>>(
        cls_logits, box_preds, gt_boxes, gt_labels, gt_masks, partials, out);
}